// Round 3
// baseline (178.153 us; speedup 1.0000x reference)
//
#include <hip/hip_runtime.h>
#include <math.h>

// Geodesic loss: mean over B of acos(clip((sum_ij m1*m2 - 1)*0.5, -1, 1)).
// R2 lesson: per-thread-contiguous float4 reads are NOT wave-coalesced
// (64 lanes at 144B stride per instruction -> TA request-bound, 1.65 TB/s,
// VALUBusy 3%). Fix: coalesced async global->LDS staging via
// global_load_lds (contiguous 1KB per wave-instruction, MLP independent of
// regalloc), then redistribute from LDS at stride-9 float reads
// (odd stride -> 2 lanes/bank -> conflict-free per m136).

#define TPB 256
#define MPB 512                  // matrices per block tile
#define FLOATS_PER_IN 4608       // 9 * MPB floats per input per tile
#define F4_PER_IN 1152           // FLOATS_PER_IN / 4

typedef const __attribute__((address_space(1))) float4 g_f4;
typedef __attribute__((address_space(3))) float4 l_f4;

__global__ __launch_bounds__(TPB) void geo_kernel(
    const float* __restrict__ a, const float* __restrict__ b,
    float* __restrict__ out, float invM, int M)
{
    __shared__ float lds[2 * FLOATS_PER_IN];   // A tile then B tile, 36 KB
    __shared__ float wsum[TPB / 64];

    const int tid = threadIdx.x;
    const long long tile_m0 = (long long)blockIdx.x * MPB;
    float sum = 0.0f;

    if (tile_m0 + MPB <= M) {
        const float4* a4 = (const float4*)(a + tile_m0 * 9);
        const float4* b4 = (const float4*)(b + tile_m0 * 9);
        const int wave_base = tid & ~63;       // wave-uniform lane-0 index

        // 1152 float4 per input: k=0..3 all waves, + waves 0,1 once more.
        // Each global_load_lds: 64 lanes x 16B = contiguous 1KB, async.
        #pragma unroll
        for (int k = 0; k < 4; ++k) {
            const int idx = k * 256 + tid;         // per-lane global index
            const int uni = k * 256 + wave_base;   // wave-uniform LDS base
            __builtin_amdgcn_global_load_lds((g_f4*)(a4 + idx),
                (l_f4*)((float4*)lds + uni), 16, 0, 0);
            __builtin_amdgcn_global_load_lds((g_f4*)(b4 + idx),
                (l_f4*)((float4*)lds + F4_PER_IN + uni), 16, 0, 0);
        }
        if (tid < 128) {   // wave-uniform branch (waves 0,1)
            const int idx = 1024 + tid;
            const int uni = 1024 + wave_base;
            __builtin_amdgcn_global_load_lds((g_f4*)(a4 + idx),
                (l_f4*)((float4*)lds + uni), 16, 0, 0);
            __builtin_amdgcn_global_load_lds((g_f4*)(b4 + idx),
                (l_f4*)((float4*)lds + F4_PER_IN + uni), 16, 0, 0);
        }
        __syncthreads();   // compiler drains vmcnt(0) before s_barrier

        const float* al = lds;
        const float* bl = lds + FLOATS_PER_IN;
        // thread tid owns matrices {tid, tid+256}: LDS float index
        // 9*tid + (2304*c + j) -> one base reg + immediate offsets,
        // stride 9 across lanes -> exactly 2 lanes/bank (free).
        #pragma unroll
        for (int c = 0; c < 2; ++c) {
            float d = 0.0f;
            #pragma unroll
            for (int j = 0; j < 9; ++j)
                d = fmaf(al[9 * tid + 2304 * c + j],
                         bl[9 * tid + 2304 * c + j], d);
            float cv = fminf(1.0f, fmaxf(-1.0f, (d - 1.0f) * 0.5f));
            sum += acosf(cv);
        }
    } else {
        // partial tail tile (unused for B=2^21; kept for generality)
        for (int c = 0; c < 2; ++c) {
            long long m = tile_m0 + tid + 256 * c;
            if (m < M) {
                float d = 0.0f;
                for (int j = 0; j < 9; ++j)
                    d = fmaf(a[m * 9 + j], b[m * 9 + j], d);
                float cv = fminf(1.0f, fmaxf(-1.0f, (d - 1.0f) * 0.5f));
                sum += acosf(cv);
            }
        }
    }

    // wave shuffle reduce -> per-block LDS reduce -> one atomic per block
    #pragma unroll
    for (int off = 32; off > 0; off >>= 1)
        sum += __shfl_down(sum, off, 64);
    const int lane = tid & 63;
    const int wid  = tid >> 6;
    if (lane == 0) wsum[wid] = sum;
    __syncthreads();
    if (tid == 0) {
        float s = 0.0f;
        #pragma unroll
        for (int i = 0; i < TPB / 64; ++i) s += wsum[i];
        atomicAdd(out, s * invM);   // device-scope by default
    }
}

extern "C" void kernel_launch(void* const* d_in, const int* in_sizes, int n_in,
                              void* d_out, int out_size, void* d_ws, size_t ws_size,
                              hipStream_t stream) {
    const float* a = (const float*)d_in[0];
    const float* b = (const float*)d_in[1];
    float* out = (float*)d_out;

    const int n = in_sizes[0];   // flat float count = 9*M
    const int M = n / 9;         // number of 3x3 matrices

    const int grid = (M + MPB - 1) / MPB;   // 4096 for B=2^21

    // d_out is re-poisoned 0xAA before every timed launch; zero it (async,
    // graph-capture safe), then accumulate the mean with per-block atomics.
    hipMemsetAsync(out, 0, (size_t)out_size * sizeof(float), stream);
    geo_kernel<<<grid, TPB, 0, stream>>>(a, b, out, 1.0f / (float)M, M);
}

// Round 4
// 166.956 us; speedup vs baseline: 1.0671x; 1.0671x over previous
//
#include <hip/hip_runtime.h>
#include <math.h>

// Geodesic loss: mean over B of acos(clip((sum_ij m1*m2 - 1)*0.5, -1, 1)).
// R3 lesson: global_load_lds (LDS-DMA) staging has shallow outstanding-queue
// depth -> only ~6-8KB/CU in flight -> 2.4 TB/s, regardless of occupancy.
// R4: stream both inputs with plain coalesced grid-stride float4 loads into
// registers (the m13 copy idiom, proven 6.29 TB/s), multiply in registers,
// stage only the PRODUCTS through LDS (ds_write_b128, conflict-free), then
// regroup: thread t sums 9 consecutive products per matrix (lane stride 9
// floats = odd = 2 lanes/bank = free) and does clamp+acos.

#define TPB 256
#define MPB 1024                 // matrices per block tile
#define F_PER_TILE 9216          // 9*MPB floats per input
#define F4_PER_TILE 2304         // F_PER_TILE/4 float4 per input

__global__ __launch_bounds__(TPB) void geo_kernel(
    const float* __restrict__ a, const float* __restrict__ b,
    float* __restrict__ out, float invM, int M)
{
    __shared__ float prod[F_PER_TILE];   // 36 KB: elementwise products
    __shared__ float wsum[TPB / 64];

    const int tid = threadIdx.x;
    const long long tile_m0 = (long long)blockIdx.x * MPB;
    float sum = 0.0f;

    if (tile_m0 + MPB <= M) {
        const float4* __restrict__ a4 = (const float4*)(a + tile_m0 * 9);
        const float4* __restrict__ b4 = (const float4*)(b + tile_m0 * 9);
        // Phase 1: 9 independent coalesced float4 load-pairs per thread.
        #pragma unroll
        for (int k = 0; k < 9; ++k) {
            const int i = k * TPB + tid;          // consecutive lanes -> 1KB/instr
            float4 va = a4[i];
            float4 vb = b4[i];
            float4 p;
            p.x = va.x * vb.x; p.y = va.y * vb.y;
            p.z = va.z * vb.z; p.w = va.w * vb.w;
            ((float4*)prod)[i] = p;               // b128 write, conflict-free
        }
        __syncthreads();
        // Phase 2: thread t owns matrices {t, t+256, t+512, t+768}.
        #pragma unroll
        for (int c = 0; c < 4; ++c) {
            const int base = 9 * (tid + 256 * c); // lane stride 9 floats: free
            float d = ((prod[base + 0] + prod[base + 1]) +
                       (prod[base + 2] + prod[base + 3])) +
                      ((prod[base + 4] + prod[base + 5]) +
                       (prod[base + 6] + prod[base + 7])) + prod[base + 8];
            float cv = fminf(1.0f, fmaxf(-1.0f, (d - 1.0f) * 0.5f));
            sum += acosf(cv);
        }
    } else {
        // partial tail tile (unused for B=2^21; kept for generality)
        for (int c = 0; c < 4; ++c) {
            long long m = tile_m0 + tid + 256 * c;
            if (m < M) {
                float d = 0.0f;
                for (int j = 0; j < 9; ++j)
                    d = fmaf(a[m * 9 + j], b[m * 9 + j], d);
                float cv = fminf(1.0f, fmaxf(-1.0f, (d - 1.0f) * 0.5f));
                sum += acosf(cv);
            }
        }
    }

    // wave shuffle reduce -> per-block LDS reduce -> one atomic per block
    #pragma unroll
    for (int off = 32; off > 0; off >>= 1)
        sum += __shfl_down(sum, off, 64);
    const int lane = tid & 63;
    const int wid  = tid >> 6;
    if (lane == 0) wsum[wid] = sum;
    __syncthreads();
    if (tid == 0) {
        float s = 0.0f;
        #pragma unroll
        for (int i = 0; i < TPB / 64; ++i) s += wsum[i];
        atomicAdd(out, s * invM);   // device-scope by default
    }
}

extern "C" void kernel_launch(void* const* d_in, const int* in_sizes, int n_in,
                              void* d_out, int out_size, void* d_ws, size_t ws_size,
                              hipStream_t stream) {
    const float* a = (const float*)d_in[0];
    const float* b = (const float*)d_in[1];
    float* out = (float*)d_out;

    const int n = in_sizes[0];   // flat float count = 9*M
    const int M = n / 9;         // number of 3x3 matrices

    const int grid = (M + MPB - 1) / MPB;   // 2048 for B=2^21

    // d_out is re-poisoned 0xAA before every timed launch; zero it (async,
    // graph-capture safe), then accumulate the mean with per-block atomics.
    hipMemsetAsync(out, 0, (size_t)out_size * sizeof(float), stream);
    geo_kernel<<<grid, TPB, 0, stream>>>(a, b, out, 1.0f / (float)M, M);
}

// Round 6
// 166.732 us; speedup vs baseline: 1.0685x; 1.0013x over previous
//
#include <hip/hip_runtime.h>
#include <math.h>

// Geodesic loss: mean over B of acos(clip((sum_ij m1*m2 - 1)*0.5, -1, 1)).
// R1-R5 lesson: every one-tile-per-block variant runs ~55us -- even fully
// LLC-cached replays -- because the load->vmcnt(0)->consume->die structure
// never has more than ~4KB/CU in flight. R6: persistent blocks (grid=512,
// 2/CU co-resident), register double-buffer across tiles: while consuming
// tile t (products->LDS->regroup->acos), tile t+1's 18 coalesced float4
// loads are already in flight in the other register set (wait becomes
// vmcnt(18), not vmcnt(0)). Compiler fence (asm memory clobber) pins issue
// order; no sched_barrier (R5 crash). ~190 VGPR = 2 waves/SIMD, matching
// the 2-blocks/CU LDS budget (72KB) -- the registers are free.

#define TPB 256
#define MPB 1024                 // matrices per tile
#define F_PER_TILE 9216          // 9*MPB floats per input per tile
#define F4_PER_TILE 2304         // float4 per input per tile
#define NBLOCKS 512              // persistent: 2 blocks/CU on 256 CUs

#define DECL(S)                                                             \
    float4 S##A0, S##A1, S##A2, S##A3, S##A4, S##A5, S##A6, S##A7, S##A8,   \
           S##B0, S##B1, S##B2, S##B3, S##B4, S##B5, S##B6, S##B7, S##B8;

// 18 coalesced loads (each wave-instr = contiguous 1KB) into register set S
#define LOADSET(S, t)                                                       \
    {                                                                       \
        const float4* __restrict__ pa = (const float4*)a + (t) * F4_PER_TILE + tid; \
        const float4* __restrict__ pb = (const float4*)b + (t) * F4_PER_TILE + tid; \
        S##A0 = pa[0];    S##A1 = pa[256];  S##A2 = pa[512];                \
        S##A3 = pa[768];  S##A4 = pa[1024]; S##A5 = pa[1280];               \
        S##A6 = pa[1536]; S##A7 = pa[1792]; S##A8 = pa[2048];               \
        S##B0 = pb[0];    S##B1 = pb[256];  S##B2 = pb[512];                \
        S##B3 = pb[768];  S##B4 = pb[1024]; S##B5 = pb[1280];               \
        S##B6 = pb[1536]; S##B7 = pb[1792]; S##B8 = pb[2048];               \
    }

#define PK(S, k)                                                            \
    {                                                                       \
        float4 p;                                                           \
        p.x = S##A##k.x * S##B##k.x; p.y = S##A##k.y * S##B##k.y;           \
        p.z = S##A##k.z * S##B##k.z; p.w = S##A##k.w * S##B##k.w;           \
        ((float4*)prod)[k * 256 + tid] = p;                                 \
    }

// products -> LDS, regroup (lane stride 9 floats = odd = conflict-free),
// clamp + acos, accumulate into `sum`
#define CONSUME(S)                                                          \
    {                                                                       \
        PK(S, 0) PK(S, 1) PK(S, 2) PK(S, 3) PK(S, 4)                        \
        PK(S, 5) PK(S, 6) PK(S, 7) PK(S, 8)                                 \
        __syncthreads();                                                    \
        _Pragma("unroll")                                                   \
        for (int c = 0; c < 4; ++c) {                                       \
            const int bsx = 9 * (tid + 256 * c);                            \
            float d = ((prod[bsx + 0] + prod[bsx + 1]) +                    \
                       (prod[bsx + 2] + prod[bsx + 3])) +                   \
                      ((prod[bsx + 4] + prod[bsx + 5]) +                    \
                       (prod[bsx + 6] + prod[bsx + 7])) + prod[bsx + 8];    \
            float cv = fminf(1.0f, fmaxf(-1.0f, (d - 1.0f) * 0.5f));        \
            sum += acosf(cv);                                               \
        }                                                                   \
        __syncthreads();                                                    \
    }

__global__ __launch_bounds__(TPB) void geo_kernel(
    const float* __restrict__ a, const float* __restrict__ b,
    float* __restrict__ out, float invM, int M)
{
    __shared__ float prod[F_PER_TILE];   // 36 KB: elementwise products
    __shared__ float wsum[TPB / 64];

    const int tid = threadIdx.x;
    float sum = 0.0f;

    const long long ntf = (long long)M / MPB;   // full tiles
    DECL(X) DECL(Y)

    long long tile = blockIdx.x;
    if (tile < ntf) {
        LOADSET(X, tile)
        int phase = 0;
        for (;;) {                                // block-uniform control
            const long long next = tile + gridDim.x;
            const bool more = (next < ntf);
            if (phase == 0) {
                if (more) LOADSET(Y, next)        // prefetch: in flight across
                asm volatile("" ::: "memory");    //   the whole consume phase
                CONSUME(X)
            } else {
                if (more) LOADSET(X, next)
                asm volatile("" ::: "memory");
                CONSUME(Y)
            }
            if (!more) break;
            tile = next;
            phase ^= 1;
        }
    }

    // tail matrices beyond the last full tile (empty for B=2^21)
    {
        const long long gid    = (long long)blockIdx.x * TPB + tid;
        const long long stride = (long long)gridDim.x * TPB;
        for (long long m = ntf * MPB + gid; m < M; m += stride) {
            float d = 0.0f;
            for (int j = 0; j < 9; ++j)
                d = fmaf(a[m * 9 + j], b[m * 9 + j], d);
            float cv = fminf(1.0f, fmaxf(-1.0f, (d - 1.0f) * 0.5f));
            sum += acosf(cv);
        }
    }

    // wave shuffle reduce -> per-block LDS reduce -> one atomic per block
    #pragma unroll
    for (int off = 32; off > 0; off >>= 1)
        sum += __shfl_down(sum, off, 64);
    const int lane = tid & 63;
    const int wid  = tid >> 6;
    if (lane == 0) wsum[wid] = sum;
    __syncthreads();
    if (tid == 0) {
        float s = 0.0f;
        #pragma unroll
        for (int i = 0; i < TPB / 64; ++i) s += wsum[i];
        atomicAdd(out, s * invM);   // device-scope by default
    }
}

extern "C" void kernel_launch(void* const* d_in, const int* in_sizes, int n_in,
                              void* d_out, int out_size, void* d_ws, size_t ws_size,
                              hipStream_t stream) {
    const float* a = (const float*)d_in[0];
    const float* b = (const float*)d_in[1];
    float* out = (float*)d_out;

    const int n = in_sizes[0];   // flat float count = 9*M
    const int M = n / 9;         // number of 3x3 matrices

    // d_out is re-poisoned 0xAA before every timed launch; zero it (async,
    // graph-capture safe), then accumulate the mean with per-block atomics.
    hipMemsetAsync(out, 0, (size_t)out_size * sizeof(float), stream);
    geo_kernel<<<NBLOCKS, TPB, 0, stream>>>(a, b, out, 1.0f / (float)M, M);
}